// Round 4
// baseline (493.780 us; speedup 1.0000x reference)
//
#include <hip/hip_runtime.h>
#include <hip/hip_fp16.h>

#define BATCH 8
#define MAX_SEQ 2048
#define HEAD_NUM 8

typedef float vfloat4 __attribute__((ext_vector_type(4)));
typedef int   vint4   __attribute__((ext_vector_type(4)));

// Output-linear mapping: one block = 2048 consecutive OUTPUT elements written
// as two unit-stride coalesced int4 chunks (plain stores -> L2 write-combine,
// same path as the 6.3 TB/s fill kernel). Head index is wave-uniform per
// block (head chunk s^2 >= 65536 is a multiple of 2048). Row divide rem/s
// uses an exact magic-multiply (s = 256k, M = floor(2^32/k)+1, shift 40;
// exact for rem < 2^22). Reads re-fetch each crop once per head; all crops
// total 53.5 MB << 256 MB L3.
__global__ __launch_bounds__(256) void genmask_kernel(
    const float* __restrict__ mask,   // (BATCH, 1, MAX_SEQ, MAX_SEQ) f32
    const int*   __restrict__ sl,     // (BATCH,) int32 seq lengths
    int*         __restrict__ out)    // packed output, int32 0/1 (bool)
{
    const unsigned int blk = blockIdx.x;

    // Which batch does this block's output chunk belong to? (wave-uniform)
    unsigned long long out_base = 0;      // element offset of batch b's region
    unsigned int blocks_before = 0;
    unsigned int s = 0;
    int b = 0;
    for (; b < BATCH; ++b) {
        s = (unsigned int)sl[b];
        // 8 heads * s^2 elems per batch, 2048 elems per block (s^2 % 2048 == 0)
        const unsigned int nb = (s * s) >> 8;   // 8*s*s/2048
        if (blk < blocks_before + nb) break;
        blocks_before += nb;
        out_base += (unsigned long long)HEAD_NUM * s * s;
    }

    const unsigned int ss = s * s;
    // Block-local element base within this batch's output region [0, 8*ss).
    unsigned int base = (blk - blocks_before) * 2048u;

    // Wave-uniform head peel: base mod ss (<= 7 scalar iterations).
    unsigned int rem_base = base;
    #pragma unroll
    for (int t = 0; t < HEAD_NUM - 1; ++t)
        if (rem_base >= ss) rem_base -= ss;

    // Magic for exact rem/s: s = 256*k, i = (rem * M) >> 40, M = floor(2^32/k)+1.
    static const unsigned long long Mtab[9] = {
        0ull,
        (1ull << 32) + 1,   // k=1
        (1ull << 31) + 1,   // k=2
        1431655766ull,      // k=3
        (1ull << 30) + 1,   // k=4
        858993460ull,       // k=5
        715827883ull,       // k=6
        613566757ull,       // k=7
        (1ull << 29) + 1    // k=8
    };
    const unsigned long long M = Mtab[s >> 8];

    const float*  in_b  = mask + (size_t)b * MAX_SEQ * MAX_SEQ;
    int*          out_p = out + out_base + base;
    const __half  half_pt5 = __float2half(0.5f);

    #pragma unroll
    for (int c = 0; c < 2; ++c) {
        const unsigned int rem = rem_base + c * 1024u + threadIdx.x * 4u;
        const unsigned int i = (unsigned int)(((unsigned long long)rem * M) >> 40);
        const unsigned int j = rem - i * s;    // multiple of 4

        const vfloat4 v = *(const vfloat4*)(in_b + (size_t)i * MAX_SEQ + j);

        vint4 r;
        r.x = __hgt(__float2half(v.x), half_pt5) ? 1 : 0;
        r.y = __hgt(__float2half(v.y), half_pt5) ? 1 : 0;
        r.z = __hgt(__float2half(v.z), half_pt5) ? 1 : 0;
        r.w = __hgt(__float2half(v.w), half_pt5) ? 1 : 0;

        *(vint4*)(out_p + c * 1024u + threadIdx.x * 4u) = r;
    }
}

extern "C" void kernel_launch(void* const* d_in, const int* in_sizes, int n_in,
                              void* d_out, int out_size, void* d_ws, size_t ws_size,
                              hipStream_t stream) {
    const float* mask = (const float*)d_in[0];
    const int*   sl   = (const int*)d_in[1];
    int*         out  = (int*)d_out;

    // 2048 output elements per block.
    const unsigned int n_blocks = (unsigned int)(out_size / 2048);

    genmask_kernel<<<n_blocks, 256, 0, stream>>>(mask, sl, out);
}